// Round 1
// baseline (339.632 us; speedup 1.0000x reference)
//
#include <hip/hip_runtime.h>
#include <math.h>

#define BATCH 64
#define IN 8000
#define OC 10
#define DD 16
#define EE 8
// per-pass partial block size in floats: BATCH*OC*DD
#define SVOL (BATCH * OC * DD)   // 10240

// Kernel A: one block handles a chunk of i-values for ALL 64 batches.
// threads: 256 = 64 b * 4 quads; thread owns d in [t4*4, t4*4+4)
// Computes partial s[b,o,d] = sum_i c[b,o,i] * u_hat[b,o,i,d] for its i-chunk.
// uniform==1: c = 0.1 (iteration 0, b-logits are all zero)
// else: logits[o] = u_hat[b,o,i,:].Vacc[b,o,:], c = softmax over o.
__global__ __launch_bounds__(256) void caps_pass(
    const float* __restrict__ W, const float* __restrict__ x,
    const float* __restrict__ Vacc, float* __restrict__ part,
    int ci, int uniform)
{
    // W tile in LDS, swizzled: element (d,e) of an (ii,o) tile stored at word
    // d*8 + e + (d>>2)*8  -> the four per-instruction addresses (one per t4)
    // land on distinct bank groups. Row size 152 words.
    __shared__ float Wl[4][OC][152];
    __shared__ float xl[4][BATCH][EE];

    const int t  = threadIdx.x;
    const int b  = t >> 2;
    const int t4 = t & 3;
    const int i0 = blockIdx.x * ci;
    int iend = i0 + ci;
    if (iend > IN) iend = IN;

    float vac[OC][4];
#pragma unroll
    for (int o = 0; o < OC; ++o)
#pragma unroll
        for (int k = 0; k < 4; ++k) vac[o][k] = 0.f;
    if (!uniform) {
        const float* vp = Vacc + b * (OC * DD) + t4 * 4;
#pragma unroll
        for (int o = 0; o < OC; ++o) {
            float4 v4 = *(const float4*)(vp + o * DD);
            vac[o][0] = v4.x; vac[o][1] = v4.y; vac[o][2] = v4.z; vac[o][3] = v4.w;
        }
    }

    float acc[OC][4];
#pragma unroll
    for (int o = 0; o < OC; ++o)
#pragma unroll
        for (int k = 0; k < 4; ++k) acc[o][k] = 0.f;

    for (int is = i0; is < iend; is += 4) {
        const int nb = min(4, iend - is);
        __syncthreads();
        // stage W: nb * 10 * 128 floats = nb*320 float4
        for (int j = t; j < nb * 320; j += 256) {
            int ii = j / 320;
            int r  = j - ii * 320;
            int o  = r >> 5;
            int f  = r & 31;
            float4 w4 = *(const float4*)(W + (size_t)o * (IN * 128) +
                                         (size_t)(is + ii) * 128 + f * 4);
            *(float4*)&Wl[ii][o][(f << 2) + ((f >> 3) << 3)] = w4;
        }
        // stage x: nb * 64 * 8 floats = nb*128 float4
        for (int j = t; j < nb * 128; j += 256) {
            int ii = j >> 7;
            int r  = j & 127;
            int b2 = r >> 1;
            int h  = r & 1;
            float4 x4 = *(const float4*)(x + (size_t)b2 * (IN * EE) +
                                         (size_t)(is + ii) * EE + h * 4);
            *(float4*)&xl[ii][b2][h * 4] = x4;
        }
        __syncthreads();

        for (int ii = 0; ii < nb; ++ii) {
            float4 xa = *(const float4*)&xl[ii][b][0];
            float4 xb = *(const float4*)&xl[ii][b][4];

            float uh[OC][4];
            float lg[OC];
#pragma unroll
            for (int o = 0; o < OC; ++o) {
                float lp = 0.f;
#pragma unroll
                for (int k = 0; k < 4; ++k) {
                    const float4* wp = (const float4*)&Wl[ii][o][t4 * 40 + k * 8];
                    float4 wa = wp[0], wb = wp[1];
                    float u = wa.x * xa.x + wa.y * xa.y + wa.z * xa.z + wa.w * xa.w
                            + wb.x * xb.x + wb.y * xb.y + wb.z * xb.z + wb.w * xb.w;
                    uh[o][k] = u;
                    lp += u * vac[o][k];
                }
                lg[o] = lp;
            }

            float c[OC];
            if (uniform) {
#pragma unroll
                for (int o = 0; o < OC; ++o) c[o] = 0.1f;
            } else {
                // reduce logits over the 4 lanes (t4) of this b
#pragma unroll
                for (int o = 0; o < OC; ++o) {
                    lg[o] += __shfl_xor(lg[o], 1);
                    lg[o] += __shfl_xor(lg[o], 2);
                }
                float mx = lg[0];
#pragma unroll
                for (int o = 1; o < OC; ++o) mx = fmaxf(mx, lg[o]);
                float sum = 0.f;
#pragma unroll
                for (int o = 0; o < OC; ++o) { c[o] = __expf(lg[o] - mx); sum += c[o]; }
                float rs = 1.f / sum;
#pragma unroll
                for (int o = 0; o < OC; ++o) c[o] *= rs;
            }
#pragma unroll
            for (int o = 0; o < OC; ++o)
#pragma unroll
                for (int k = 0; k < 4; ++k) acc[o][k] += c[o] * uh[o][k];
        }
    }

    float* pp = part + (size_t)blockIdx.x * SVOL + b * (OC * DD) + t4 * 4;
#pragma unroll
    for (int o = 0; o < OC; ++o) {
        float4 v4 = make_float4(acc[o][0], acc[o][1], acc[o][2], acc[o][3]);
        *(float4*)(pp + o * DD) = v4;
    }
}

// Kernel B: one block per (b,o). Reduce partials over nblk blocks, squash,
// accumulate into Vacc (or write final v to out).
__global__ __launch_bounds__(256) void caps_reduce(
    const float* __restrict__ part, float* __restrict__ Vacc,
    float* __restrict__ out, int nblk, int last)
{
    const int bo = blockIdx.x;      // [0, 640)
    const int t  = threadIdx.x;
    const int d  = t & 15;
    const int s  = t >> 4;          // 16 slices of the blk range

    float acc = 0.f;
    for (int blk = s; blk < nblk; blk += 16)
        acc += part[(size_t)blk * SVOL + bo * DD + d];

    __shared__ float red[16][17];
    red[s][d] = acc;
    __syncthreads();
    if (t < 16) {
        float sv = 0.f;
#pragma unroll
        for (int s2 = 0; s2 < 16; ++s2) sv += red[s2][t];
        // squash: norm over d across lanes 0..15
        float n2 = sv * sv;
#pragma unroll
        for (int m = 1; m < 16; m <<= 1) n2 += __shfl_xor(n2, m);
        float norm  = sqrtf(n2);
        float scale = n2 / (1.f + n2) / (norm + 1e-8f);
        float v = scale * sv;
        if (last) out[bo * DD + t] = v;
        else      Vacc[bo * DD + t] += v;
    }
}

extern "C" void kernel_launch(void* const* d_in, const int* in_sizes, int n_in,
                              void* d_out, int out_size, void* d_ws, size_t ws_size,
                              hipStream_t stream) {
    const float* x = (const float*)d_in[0];   // (64, 8000, 8)
    const float* W = (const float*)d_in[1];   // (10, 8000, 16, 8)
    float* out = (float*)d_out;               // (64, 10, 16)

    char* ws = (char*)d_ws;
    float* Vacc = (float*)ws;                           // 10240 floats = 40 KB
    float* part = (float*)(ws + SVOL * sizeof(float));  // nblk * 10240 floats

    size_t avail = (ws_size > SVOL * sizeof(float)) ? ws_size - SVOL * sizeof(float) : 0;
    int nblk = (int)(avail / (SVOL * sizeof(float)));
    if (nblk > 400) nblk = 400;
    if (nblk < 1)   nblk = 1;
    int ci = (IN + nblk - 1) / nblk;
    nblk = (IN + ci - 1) / ci;

    hipMemsetAsync(Vacc, 0, SVOL * sizeof(float), stream);

    // iter 0: uniform c
    caps_pass<<<nblk, 256, 0, stream>>>(W, x, Vacc, part, ci, 1);
    caps_reduce<<<640, 256, 0, stream>>>(part, Vacc, out, nblk, 0);
    // iter 1
    caps_pass<<<nblk, 256, 0, stream>>>(W, x, Vacc, part, ci, 0);
    caps_reduce<<<640, 256, 0, stream>>>(part, Vacc, out, nblk, 0);
    // iter 2 (final): write v to out
    caps_pass<<<nblk, 256, 0, stream>>>(W, x, Vacc, part, ci, 0);
    caps_reduce<<<640, 256, 0, stream>>>(part, Vacc, out, nblk, 1);
}

// Round 2
// 331.875 us; speedup vs baseline: 1.0234x; 1.0234x over previous
//
#include <hip/hip_runtime.h>
#include <math.h>

#define BATCH 64
#define IN 8000
#define OC 10
#define DD 16
#define EE 8
#define BG 16                      // batches per block
#define PVOL (BG * OC * DD)        // 2560 floats per block partial
#define SVOL (BATCH * OC * DD)     // 10240 floats (Vacc)

// Kernel A: block = (batch-group bg of 16 b) x (i-chunk). 256 threads =
// 4 waves; wave ii owns i-slot is+ii of each 4-i stage (no inner ii loop).
// Within a wave: lane = bl*4 + t4; thread owns d in [t4*4, t4*4+4) for
// batch b = bg*16+bl. Per-thread partial acc[o][4] summed over its i's;
// cross-wave LDS reduce at the end, one 10KB partial per block.
template<int UNIFORM>
__global__ __launch_bounds__(256) void caps_pass(
    const float* __restrict__ W, const float* __restrict__ x,
    const float* __restrict__ Vacc, float* __restrict__ part,
    int ci)
{
    // W tile swizzled: element (d,e) of an (ii,o) tile at word
    // d*8 + e + (d>>2)*8 -> per-instruction addresses (one per t4) hit
    // disjoint bank groups. Row 152 words.
    __shared__ float Wl[4][OC][152];   // 24320 B
    __shared__ float xl[4][BG][12];    // 3072 B, stride 12 words (48B, 16B-aligned)

    const int t    = threadIdx.x;
    const int ii   = t >> 6;           // wave index = i-slot within stage
    const int lane = t & 63;
    const int bl   = lane >> 2;        // local batch 0..15
    const int t4   = lane & 3;         // d-quad
    const int bg   = blockIdx.x;       // batch group 0..3
    const int b    = bg * BG + bl;
    const int i0   = blockIdx.y * ci;
    int iend = i0 + ci;
    if (iend > IN) iend = IN;

    float vac[OC][4];
    if (!UNIFORM) {
        const float* vp = Vacc + b * (OC * DD) + t4 * 4;
#pragma unroll
        for (int o = 0; o < OC; ++o) {
            float4 v4 = *(const float4*)(vp + o * DD);
            vac[o][0] = v4.x; vac[o][1] = v4.y; vac[o][2] = v4.z; vac[o][3] = v4.w;
        }
    }

    float acc[OC][4];
#pragma unroll
    for (int o = 0; o < OC; ++o)
#pragma unroll
        for (int k = 0; k < 4; ++k) acc[o][k] = 0.f;

    for (int is = i0; is < iend; is += 4) {
        const int nb = min(4, iend - is);
        __syncthreads();
        // stage W: nb*10*32 float4 (5 per thread when nb=4)
        for (int j = t; j < nb * 320; j += 256) {
            int iw = j / 320;
            int r  = j - iw * 320;
            int o  = r >> 5;
            int f  = r & 31;
            float4 w4 = *(const float4*)(W + (size_t)o * (IN * 128) +
                                         (size_t)(is + iw) * 128 + f * 4);
            *(float4*)&Wl[iw][o][(f << 2) + ((f >> 3) << 3)] = w4;
        }
        // stage x: nb*16*2 float4
        for (int j = t; j < nb * BG * 2; j += 256) {
            int iw = j >> 5;
            int r  = j & 31;
            int b2 = r >> 1;
            int h  = r & 1;
            float4 x4 = *(const float4*)(x + (size_t)(bg * BG + b2) * (IN * EE) +
                                         (size_t)(is + iw) * EE + h * 4);
            *(float4*)&xl[iw][b2][h * 4] = x4;
        }
        __syncthreads();

        if (ii < nb) {
            float4 xa = *(const float4*)&xl[ii][bl][0];
            float4 xb = *(const float4*)&xl[ii][bl][4];

            float uh[OC][4];
            float lg[OC];
#pragma unroll
            for (int o = 0; o < OC; ++o) {
                float lp = 0.f;
#pragma unroll
                for (int k = 0; k < 4; ++k) {
                    const float4* wp = (const float4*)&Wl[ii][o][t4 * 40 + k * 8];
                    float4 wa = wp[0], wb = wp[1];
                    float u = wa.x * xa.x + wa.y * xa.y + wa.z * xa.z + wa.w * xa.w
                            + wb.x * xb.x + wb.y * xb.y + wb.z * xb.z + wb.w * xb.w;
                    uh[o][k] = u;
                    if (!UNIFORM) lp += u * vac[o][k];
                }
                lg[o] = lp;
            }

            if (UNIFORM) {
#pragma unroll
                for (int o = 0; o < OC; ++o)
#pragma unroll
                    for (int k = 0; k < 4; ++k) acc[o][k] += 0.1f * uh[o][k];
            } else {
#pragma unroll
                for (int o = 0; o < OC; ++o) {
                    lg[o] += __shfl_xor(lg[o], 1);
                    lg[o] += __shfl_xor(lg[o], 2);
                }
                float mx = lg[0];
#pragma unroll
                for (int o = 1; o < OC; ++o) mx = fmaxf(mx, lg[o]);
                float c[OC];
                float sum = 0.f;
#pragma unroll
                for (int o = 0; o < OC; ++o) { c[o] = __expf(lg[o] - mx); sum += c[o]; }
                float rs = 1.f / sum;
#pragma unroll
                for (int o = 0; o < OC; ++o) {
                    float co = c[o] * rs;
#pragma unroll
                    for (int k = 0; k < 4; ++k) acc[o][k] += co * uh[o][k];
                }
            }
        }
    }

    // cross-wave reduce: alias red[] onto Wl (6080 floats >= 2560 needed)
    float* red = &Wl[0][0][0];
    for (int g = 0; g < 4; ++g) {
        __syncthreads();
        if (ii == g) {
            float* p = red + (bl * 4 + t4) * 40;
            if (g == 0) {
#pragma unroll
                for (int o = 0; o < OC; ++o)
#pragma unroll
                    for (int k = 0; k < 4; ++k) p[o * 4 + k] = acc[o][k];
            } else {
#pragma unroll
                for (int o = 0; o < OC; ++o)
#pragma unroll
                    for (int k = 0; k < 4; ++k) p[o * 4 + k] += acc[o][k];
            }
        }
    }
    __syncthreads();
    if (ii == 0) {
        float* pp = part + ((size_t)blockIdx.y * 4 + bg) * PVOL + bl * (OC * DD) + t4 * 4;
        const float* p = red + (bl * 4 + t4) * 40;
#pragma unroll
        for (int o = 0; o < OC; ++o)
            *(float4*)(pp + o * DD) =
                make_float4(p[o * 4], p[o * 4 + 1], p[o * 4 + 2], p[o * 4 + 3]);
    }
}

// Kernel B: one block per (b,o). Reduce partials over chunks, squash,
// write Vacc (mode 0 = overwrite, 1 = accumulate) or final out (mode 2).
__global__ __launch_bounds__(256) void caps_reduce(
    const float* __restrict__ part, float* __restrict__ Vacc,
    float* __restrict__ out, int nchunk, int mode)
{
    const int bo = blockIdx.x;      // b*10+o, [0,640)
    const int t  = threadIdx.x;
    const int d  = t & 15;
    const int s  = t >> 4;          // 16 slices over chunks
    const int b  = bo / 10;
    const int o  = bo - b * 10;
    const int g  = b >> 4;
    const int bl = b & 15;

    const float* base = part + (size_t)g * PVOL + bl * (OC * DD) + o * DD + d;
    float acc = 0.f;
    for (int c = s; c < nchunk; c += 16)
        acc += base[(size_t)c * 4 * PVOL];

    __shared__ float red[16][17];
    red[s][d] = acc;
    __syncthreads();
    if (t < 16) {
        float sv = 0.f;
#pragma unroll
        for (int s2 = 0; s2 < 16; ++s2) sv += red[s2][t];
        float n2 = sv * sv;
#pragma unroll
        for (int m = 1; m < 16; m <<= 1) n2 += __shfl_xor(n2, m);
        float norm  = sqrtf(n2);
        float scale = n2 / (1.f + n2) / (norm + 1e-8f);
        float v = scale * sv;
        if (mode == 2)      out[bo * DD + t] = v;
        else if (mode == 0) Vacc[bo * DD + t] = v;
        else                Vacc[bo * DD + t] += v;
    }
}

extern "C" void kernel_launch(void* const* d_in, const int* in_sizes, int n_in,
                              void* d_out, int out_size, void* d_ws, size_t ws_size,
                              hipStream_t stream) {
    const float* x = (const float*)d_in[0];   // (64, 8000, 8)
    const float* W = (const float*)d_in[1];   // (10, 8000, 16, 8)
    float* out = (float*)d_out;               // (64, 10, 16)

    char* ws = (char*)d_ws;
    float* Vacc = (float*)ws;                             // 40 KB
    float* part = (float*)(ws + SVOL * sizeof(float));    // nchunk*4*PVOL floats

    size_t avail = (ws_size > SVOL * sizeof(float)) ? ws_size - SVOL * sizeof(float) : 0;
    int nchunk = (int)(avail / (4 * PVOL * sizeof(float)));
    if (nchunk > 250) nchunk = 250;
    if (nchunk < 1)   nchunk = 1;
    int ci = (IN + nchunk - 1) / nchunk;
    nchunk = (IN + ci - 1) / ci;

    dim3 grid(4, nchunk);   // bg fastest: 4 readers of a W chunk dispatch adjacently

    // iter 0: uniform c = 0.1 (b-logits all zero)
    caps_pass<1><<<grid, 256, 0, stream>>>(W, x, Vacc, part, ci);
    caps_reduce<<<640, 256, 0, stream>>>(part, Vacc, out, nchunk, 0);
    // iter 1
    caps_pass<0><<<grid, 256, 0, stream>>>(W, x, Vacc, part, ci);
    caps_reduce<<<640, 256, 0, stream>>>(part, Vacc, out, nchunk, 1);
    // iter 2 (final): write v to out
    caps_pass<0><<<grid, 256, 0, stream>>>(W, x, Vacc, part, ci);
    caps_reduce<<<640, 256, 0, stream>>>(part, Vacc, out, nchunk, 2);
}